// Round 3
// baseline (53.556 us; speedup 1.0000x reference)
//
#include <hip/hip_runtime.h>
#include <cmath>

#define NN 1024
#define FF 512
#define HH 64
#define NPAIRS 528   // 32*33/2 unordered pairs of 32-row tiles

// ---------------------------------------------------------------------------
// k1: h = relu(x@W1 + b1) @ W2 + b2 ; ei = h@Wa1[:H] ; ejb = h@Wa1[H:] + ba1
// 256 blocks x 256 threads, 4 rows per block, 4-way k-split.
// Thread layout: ks = tid>>6 (k-split 0..3), r = (tid>>4)&3, cg = (tid&15)*4.
// Block 0 thread 0 zeroes the arrival counter used by k2_fused.
// ---------------------------------------------------------------------------
__global__ __launch_bounds__(256) void k1_transform(
    const float* __restrict__ x, const float* __restrict__ W1,
    const float* __restrict__ b1, const float* __restrict__ W2,
    const float* __restrict__ b2, const float* __restrict__ Wa1,
    const float* __restrict__ ba1,
    float* __restrict__ ei, float* __restrict__ ejb,
    int* __restrict__ counter)
{
    __shared__ float xs[4][516];       // 516%32==4 -> bank spread
    __shared__ float ts[4][68];
    __shared__ float hs[4][68];
    __shared__ float pp[4][4][68];     // k-split partials
    const int tid = threadIdx.x;
    const int row0 = blockIdx.x * 4;

    if (blockIdx.x == 0 && tid == 0) *counter = 0;   // visible to k2 via kernel boundary

    // stage x tile [4][512]: 512 float4 / 256 threads = 2 each
    #pragma unroll
    for (int l = 0; l < 2; ++l) {
        int f4 = tid + l * 256;
        int r = f4 >> 7;
        int cc = (f4 & 127) << 2;
        *reinterpret_cast<float4*>(&xs[r][cc]) =
            *reinterpret_cast<const float4*>(x + (row0 + r) * FF + cc);
    }
    __syncthreads();

    const int ks = tid >> 6;          // 0..3  k-split quarter
    const int r  = (tid >> 4) & 3;    // row 0..3
    const int cg = (tid & 15) << 2;   // col group of 4

    // GEMM1 partial: k in [ks*128, ks*128+128)
    {
        float4 acc = make_float4(0.f, 0.f, 0.f, 0.f);
        const int k0 = ks * 128;
        #pragma unroll 4
        for (int k = k0; k < k0 + 128; k += 4) {
            float4 a  = *reinterpret_cast<const float4*>(&xs[r][k]);
            float4 w0 = *reinterpret_cast<const float4*>(W1 + (k + 0) * HH + cg);
            float4 w1 = *reinterpret_cast<const float4*>(W1 + (k + 1) * HH + cg);
            float4 w2 = *reinterpret_cast<const float4*>(W1 + (k + 2) * HH + cg);
            float4 w3 = *reinterpret_cast<const float4*>(W1 + (k + 3) * HH + cg);
            acc.x += a.x * w0.x + a.y * w1.x + a.z * w2.x + a.w * w3.x;
            acc.y += a.x * w0.y + a.y * w1.y + a.z * w2.y + a.w * w3.y;
            acc.z += a.x * w0.z + a.y * w1.z + a.z * w2.z + a.w * w3.z;
            acc.w += a.x * w0.w + a.y * w1.w + a.z * w2.w + a.w * w3.w;
        }
        *reinterpret_cast<float4*>(&pp[ks][r][cg]) = acc;
    }
    __syncthreads();
    if (ks == 0) {
        float4 p0 = *reinterpret_cast<const float4*>(&pp[0][r][cg]);
        float4 p1 = *reinterpret_cast<const float4*>(&pp[1][r][cg]);
        float4 p2 = *reinterpret_cast<const float4*>(&pp[2][r][cg]);
        float4 p3 = *reinterpret_cast<const float4*>(&pp[3][r][cg]);
        float4 bv = *reinterpret_cast<const float4*>(b1 + cg);
        float4 t;
        t.x = fmaxf((p0.x + p1.x) + (p2.x + p3.x) + bv.x, 0.f);
        t.y = fmaxf((p0.y + p1.y) + (p2.y + p3.y) + bv.y, 0.f);
        t.z = fmaxf((p0.z + p1.z) + (p2.z + p3.z) + bv.z, 0.f);
        t.w = fmaxf((p0.w + p1.w) + (p2.w + p3.w) + bv.w, 0.f);
        *reinterpret_cast<float4*>(&ts[r][cg]) = t;
    }
    __syncthreads();

    // GEMM2 partial: k in [ks*16, ks*16+16)
    {
        float4 acc = make_float4(0.f, 0.f, 0.f, 0.f);
        const int k0 = ks * 16;
        #pragma unroll
        for (int k = k0; k < k0 + 16; k += 4) {
            float4 a  = *reinterpret_cast<const float4*>(&ts[r][k]);
            float4 w0 = *reinterpret_cast<const float4*>(W2 + (k + 0) * HH + cg);
            float4 w1 = *reinterpret_cast<const float4*>(W2 + (k + 1) * HH + cg);
            float4 w2 = *reinterpret_cast<const float4*>(W2 + (k + 2) * HH + cg);
            float4 w3 = *reinterpret_cast<const float4*>(W2 + (k + 3) * HH + cg);
            acc.x += a.x * w0.x + a.y * w1.x + a.z * w2.x + a.w * w3.x;
            acc.y += a.x * w0.y + a.y * w1.y + a.z * w2.y + a.w * w3.y;
            acc.z += a.x * w0.z + a.y * w1.z + a.z * w2.z + a.w * w3.z;
            acc.w += a.x * w0.w + a.y * w1.w + a.z * w2.w + a.w * w3.w;
        }
        *reinterpret_cast<float4*>(&pp[ks][r][cg]) = acc;
    }
    __syncthreads();
    if (ks == 0) {
        float4 p0 = *reinterpret_cast<const float4*>(&pp[0][r][cg]);
        float4 p1 = *reinterpret_cast<const float4*>(&pp[1][r][cg]);
        float4 p2 = *reinterpret_cast<const float4*>(&pp[2][r][cg]);
        float4 p3 = *reinterpret_cast<const float4*>(&pp[3][r][cg]);
        float4 bv = *reinterpret_cast<const float4*>(b2 + cg);
        float4 h;
        h.x = (p0.x + p1.x) + (p2.x + p3.x) + bv.x;
        h.y = (p0.y + p1.y) + (p2.y + p3.y) + bv.y;
        h.z = (p0.z + p1.z) + (p2.z + p3.z) + bv.z;
        h.w = (p0.w + p1.w) + (p2.w + p3.w) + bv.w;
        *reinterpret_cast<float4*>(&hs[r][cg]) = h;
    }
    __syncthreads();

    // GEMM3: ks>>1 selects ei (0) / ejb (1); ks&1 selects k-half of 32
    {
        const float* Wb = Wa1 + (ks >> 1) * HH * HH;
        float4 acc = make_float4(0.f, 0.f, 0.f, 0.f);
        const int k0 = (ks & 1) * 32;
        #pragma unroll
        for (int k = k0; k < k0 + 32; k += 4) {
            float4 a  = *reinterpret_cast<const float4*>(&hs[r][k]);
            float4 w0 = *reinterpret_cast<const float4*>(Wb + (k + 0) * HH + cg);
            float4 w1 = *reinterpret_cast<const float4*>(Wb + (k + 1) * HH + cg);
            float4 w2 = *reinterpret_cast<const float4*>(Wb + (k + 2) * HH + cg);
            float4 w3 = *reinterpret_cast<const float4*>(Wb + (k + 3) * HH + cg);
            acc.x += a.x * w0.x + a.y * w1.x + a.z * w2.x + a.w * w3.x;
            acc.y += a.x * w0.y + a.y * w1.y + a.z * w2.y + a.w * w3.y;
            acc.z += a.x * w0.z + a.y * w1.z + a.z * w2.z + a.w * w3.z;
            acc.w += a.x * w0.w + a.y * w1.w + a.z * w2.w + a.w * w3.w;
        }
        *reinterpret_cast<float4*>(&pp[ks][r][cg]) = acc;
    }
    __syncthreads();
    if (ks == 0) {
        float4 p0 = *reinterpret_cast<const float4*>(&pp[0][r][cg]);
        float4 p1 = *reinterpret_cast<const float4*>(&pp[1][r][cg]);
        float4 v;
        v.x = p0.x + p1.x; v.y = p0.y + p1.y;
        v.z = p0.z + p1.z; v.w = p0.w + p1.w;
        *reinterpret_cast<float4*>(ei + (row0 + r) * HH + cg) = v;
    } else if (ks == 2) {
        float4 p2 = *reinterpret_cast<const float4*>(&pp[2][r][cg]);
        float4 p3 = *reinterpret_cast<const float4*>(&pp[3][r][cg]);
        float4 bv = *reinterpret_cast<const float4*>(ba1 + cg);
        float4 v;
        v.x = p2.x + p3.x + bv.x; v.y = p2.y + p3.y + bv.y;
        v.z = p2.z + p3.z + bv.z; v.w = p2.w + p3.w + bv.w;
        *reinterpret_cast<float4*>(ejb + (row0 + r) * HH + cg) = v;
    }
}

// ---------------------------------------------------------------------------
// k2_fused: per unordered 32-tile pair (I<=J), compute raw tiles (I,J) and
// (J,I), symmetrize + sigmoid in-register (transpose via LDS), write final
// adjacency once, accumulate deterministic partial; last-arriving block does
// the fixed-order loss reduction.  528 blocks x 256 threads.
// ---------------------------------------------------------------------------
__global__ __launch_bounds__(256) void k2_fused(
    const float* __restrict__ ei, const float* __restrict__ ejb,
    const float* __restrict__ wa2, const float* __restrict__ ba2,
    const float* __restrict__ temp,
    float* __restrict__ out, float* __restrict__ partials,
    int* __restrict__ counter, float* __restrict__ out_loss)
{
    __shared__ float stg[4][32][68];   // 0:ei_I 1:ei_J 2:ejb_I 3:ejb_J
    __shared__ float Tij[32][33];
    __shared__ float Tji[32][33];
    __shared__ float wl[64];
    __shared__ float wsum[4];
    __shared__ int lastFlag;
    const int tid = threadIdx.x;

    // decode unordered pair (I<=J), I,J in [0,32)
    int I = 0, rem = blockIdx.x, rl = 32;
    while (rem >= rl) { rem -= rl; ++I; --rl; }
    const int J = I + rem;
    const int iBase = I * 32, jBase = J * 32;
    const bool off = (I != J);

    // stage 4 tiles of 32 rows x 64: coalesced float4
    {
        const int rr = tid >> 4;          // 0..15
        const int cq = (tid & 15) << 2;
        const float* s0 = ei  + iBase * HH;
        const float* s1 = ei  + jBase * HH;
        const float* s2 = ejb + iBase * HH;
        const float* s3 = ejb + jBase * HH;
        *reinterpret_cast<float4*>(&stg[0][rr     ][cq]) = *reinterpret_cast<const float4*>(s0 + (rr     ) * HH + cq);
        *reinterpret_cast<float4*>(&stg[0][rr + 16][cq]) = *reinterpret_cast<const float4*>(s0 + (rr + 16) * HH + cq);
        *reinterpret_cast<float4*>(&stg[1][rr     ][cq]) = *reinterpret_cast<const float4*>(s1 + (rr     ) * HH + cq);
        *reinterpret_cast<float4*>(&stg[1][rr + 16][cq]) = *reinterpret_cast<const float4*>(s1 + (rr + 16) * HH + cq);
        *reinterpret_cast<float4*>(&stg[2][rr     ][cq]) = *reinterpret_cast<const float4*>(s2 + (rr     ) * HH + cq);
        *reinterpret_cast<float4*>(&stg[2][rr + 16][cq]) = *reinterpret_cast<const float4*>(s2 + (rr + 16) * HH + cq);
        *reinterpret_cast<float4*>(&stg[3][rr     ][cq]) = *reinterpret_cast<const float4*>(s3 + (rr     ) * HH + cq);
        *reinterpret_cast<float4*>(&stg[3][rr + 16][cq]) = *reinterpret_cast<const float4*>(s3 + (rr + 16) * HH + cq);
    }
    if (tid < 16) {
        *reinterpret_cast<float4*>(&wl[tid * 4]) =
            *reinterpret_cast<const float4*>(wa2 + tid * 4);
    }
    __syncthreads();

    const int c  = tid & 31;   // col within tile
    const int r0 = tid >> 5;   // 0..7 -> rows r0+8m

    float accIJ[4] = {0.f, 0.f, 0.f, 0.f};
    float accJI[4] = {0.f, 0.f, 0.f, 0.f};

    // tile (I,J): s = sum_h relu(ei_I[row,h] + ejb_J[c,h]) * w[h]
    #pragma unroll
    for (int h = 0; h < HH; h += 4) {
        float4 w  = *reinterpret_cast<const float4*>(&wl[h]);
        float4 Bj = *reinterpret_cast<const float4*>(&stg[3][c][h]);
        #pragma unroll
        for (int m = 0; m < 4; ++m) {
            float4 A = *reinterpret_cast<const float4*>(&stg[0][r0 + 8 * m][h]);
            accIJ[m] += fmaxf(A.x + Bj.x, 0.f) * w.x
                      + fmaxf(A.y + Bj.y, 0.f) * w.y
                      + fmaxf(A.z + Bj.z, 0.f) * w.z
                      + fmaxf(A.w + Bj.w, 0.f) * w.w;
        }
    }
    // tile (J,I): s = sum_h relu(ei_J[row,h] + ejb_I[c,h]) * w[h]
    if (off) {
        #pragma unroll
        for (int h = 0; h < HH; h += 4) {
            float4 w  = *reinterpret_cast<const float4*>(&wl[h]);
            float4 Bi = *reinterpret_cast<const float4*>(&stg[2][c][h]);
            #pragma unroll
            for (int m = 0; m < 4; ++m) {
                float4 A = *reinterpret_cast<const float4*>(&stg[1][r0 + 8 * m][h]);
                accJI[m] += fmaxf(A.x + Bi.x, 0.f) * w.x
                          + fmaxf(A.y + Bi.y, 0.f) * w.y
                          + fmaxf(A.z + Bi.z, 0.f) * w.z
                          + fmaxf(A.w + Bi.w, 0.f) * w.w;
            }
        }
    }

    // transpose exchange
    #pragma unroll
    for (int m = 0; m < 4; ++m) Tij[r0 + 8 * m][c] = accIJ[m];
    if (off) {
        #pragma unroll
        for (int m = 0; m < 4; ++m) Tji[r0 + 8 * m][c] = accJI[m];
    }
    __syncthreads();

    const float t = fminf(fmaxf(temp[0], 0.1f), 5.0f);
    const float invt = 1.0f / t;
    const float bb = ba2[0];

    float lsum = 0.f;
    #pragma unroll
    for (int m = 0; m < 4; ++m) {
        const int row = r0 + 8 * m;
        float sji = off ? Tji[c][row] : Tij[c][row];   // S[J*32+c][I*32+row]
        float v = (0.5f * (accIJ[m] + sji) + bb) * invt;
        float adj = 1.0f / (1.0f + expf(-v));
        out[(iBase + row) * NN + jBase + c] = adj;
        lsum += adj;
    }
    if (off) {
        #pragma unroll
        for (int m = 0; m < 4; ++m) {
            const int row = r0 + 8 * m;
            float sij = Tij[c][row];                   // S[I*32+c][J*32+row]
            float v = (0.5f * (accJI[m] + sij) + bb) * invt;
            float adj = 1.0f / (1.0f + expf(-v));
            out[(jBase + row) * NN + iBase + c] = adj;
            lsum += adj;
        }
    }

    // deterministic per-block partial: fixed shuffle tree + fixed wave order
    float w = lsum;
    #pragma unroll
    for (int o = 32; o > 0; o >>= 1) w += __shfl_down(w, o);
    if ((tid & 63) == 0) wsum[tid >> 6] = w;
    __syncthreads();
    if (tid == 0) {
        float tot = (wsum[0] + wsum[1]) + (wsum[2] + wsum[3]);
        atomicExch(&partials[blockIdx.x], tot);   // device-coherent store
        __threadfence();
        int old = atomicAdd(counter, 1);
        lastFlag = (old == NPAIRS - 1);
    }
    __syncthreads();

    if (lastFlag) {
        __threadfence();
        // fixed-order tree over 528 slots -> bitwise deterministic
        float v = atomicAdd(&partials[tid], 0.0f)
                + atomicAdd(&partials[tid + 256], 0.0f);
        if (tid < 16) v += atomicAdd(&partials[tid + 512], 0.0f);
        #pragma unroll
        for (int o = 32; o > 0; o >>= 1) v += __shfl_down(v, o);
        if ((tid & 63) == 0) wsum[tid >> 6] = v;
        __syncthreads();
        if (tid == 0) {
            float tot = (wsum[0] + wsum[1]) + (wsum[2] + wsum[3]);
            *out_loss = 0.01f * tot / (float)(NN * NN);
        }
    }
}

extern "C" void kernel_launch(void* const* d_in, const int* in_sizes, int n_in,
                              void* d_out, int out_size, void* d_ws, size_t ws_size,
                              hipStream_t stream)
{
    const float* x    = (const float*)d_in[0];
    const float* W1   = (const float*)d_in[1];
    const float* b1   = (const float*)d_in[2];
    const float* W2   = (const float*)d_in[3];
    const float* b2   = (const float*)d_in[4];
    const float* Wa1  = (const float*)d_in[5];
    const float* ba1  = (const float*)d_in[6];
    const float* wa2  = (const float*)d_in[7];
    const float* ba2  = (const float*)d_in[8];
    const float* temp = (const float*)d_in[9];
    float* out = (float*)d_out;

    float* ei    = (float*)d_ws;            // N*H floats
    float* ejb   = ei + NN * HH;            // N*H floats
    float* parts = ejb + NN * HH;           // NPAIRS floats
    int*   ctr   = (int*)(parts + NPAIRS);  // arrival counter

    k1_transform<<<NN / 4, 256, 0, stream>>>(x, W1, b1, W2, b2, Wa1, ba1, ei, ejb, ctr);
    k2_fused<<<NPAIRS, 256, 0, stream>>>(ei, ejb, wa2, ba2, temp, out, parts, ctr,
                                         out + NN * NN);
}

// Round 4
// 35.007 us; speedup vs baseline: 1.5299x; 1.5299x over previous
//
#include <hip/hip_runtime.h>
#include <cmath>

#define NN 1024
#define FF 512
#define HH 64
#define NPAIRS 528   // 32*33/2 unordered pairs of 32-row tiles

// ---------------------------------------------------------------------------
// k1: h = relu(x@W1 + b1) @ W2 + b2 ; ei = h@Wa1[:H] ; ejb = h@Wa1[H:] + ba1
// 256 blocks x 256 threads, 4 rows per block, 4-way k-split.
// ---------------------------------------------------------------------------
__global__ __launch_bounds__(256) void k1_transform(
    const float* __restrict__ x, const float* __restrict__ W1,
    const float* __restrict__ b1, const float* __restrict__ W2,
    const float* __restrict__ b2, const float* __restrict__ Wa1,
    const float* __restrict__ ba1,
    float* __restrict__ ei, float* __restrict__ ejb)
{
    __shared__ float xs[4][516];       // 516%32==4 -> bank spread
    __shared__ float ts[4][68];
    __shared__ float hs[4][68];
    __shared__ float pp[4][4][68];     // k-split partials
    const int tid = threadIdx.x;
    const int row0 = blockIdx.x * 4;

    // stage x tile [4][512]: 512 float4 / 256 threads = 2 each
    #pragma unroll
    for (int l = 0; l < 2; ++l) {
        int f4 = tid + l * 256;
        int r = f4 >> 7;
        int cc = (f4 & 127) << 2;
        *reinterpret_cast<float4*>(&xs[r][cc]) =
            *reinterpret_cast<const float4*>(x + (row0 + r) * FF + cc);
    }
    __syncthreads();

    const int ks = tid >> 6;          // 0..3  k-split quarter
    const int r  = (tid >> 4) & 3;    // row 0..3
    const int cg = (tid & 15) << 2;   // col group of 4

    // GEMM1 partial: k in [ks*128, ks*128+128)
    {
        float4 acc = make_float4(0.f, 0.f, 0.f, 0.f);
        const int k0 = ks * 128;
        #pragma unroll 4
        for (int k = k0; k < k0 + 128; k += 4) {
            float4 a  = *reinterpret_cast<const float4*>(&xs[r][k]);
            float4 w0 = *reinterpret_cast<const float4*>(W1 + (k + 0) * HH + cg);
            float4 w1 = *reinterpret_cast<const float4*>(W1 + (k + 1) * HH + cg);
            float4 w2 = *reinterpret_cast<const float4*>(W1 + (k + 2) * HH + cg);
            float4 w3 = *reinterpret_cast<const float4*>(W1 + (k + 3) * HH + cg);
            acc.x += a.x * w0.x + a.y * w1.x + a.z * w2.x + a.w * w3.x;
            acc.y += a.x * w0.y + a.y * w1.y + a.z * w2.y + a.w * w3.y;
            acc.z += a.x * w0.z + a.y * w1.z + a.z * w2.z + a.w * w3.z;
            acc.w += a.x * w0.w + a.y * w1.w + a.z * w2.w + a.w * w3.w;
        }
        *reinterpret_cast<float4*>(&pp[ks][r][cg]) = acc;
    }
    __syncthreads();
    if (ks == 0) {
        float4 p0 = *reinterpret_cast<const float4*>(&pp[0][r][cg]);
        float4 p1 = *reinterpret_cast<const float4*>(&pp[1][r][cg]);
        float4 p2 = *reinterpret_cast<const float4*>(&pp[2][r][cg]);
        float4 p3 = *reinterpret_cast<const float4*>(&pp[3][r][cg]);
        float4 bv = *reinterpret_cast<const float4*>(b1 + cg);
        float4 t;
        t.x = fmaxf((p0.x + p1.x) + (p2.x + p3.x) + bv.x, 0.f);
        t.y = fmaxf((p0.y + p1.y) + (p2.y + p3.y) + bv.y, 0.f);
        t.z = fmaxf((p0.z + p1.z) + (p2.z + p3.z) + bv.z, 0.f);
        t.w = fmaxf((p0.w + p1.w) + (p2.w + p3.w) + bv.w, 0.f);
        *reinterpret_cast<float4*>(&ts[r][cg]) = t;
    }
    __syncthreads();

    // GEMM2 partial: k in [ks*16, ks*16+16)
    {
        float4 acc = make_float4(0.f, 0.f, 0.f, 0.f);
        const int k0 = ks * 16;
        #pragma unroll
        for (int k = k0; k < k0 + 16; k += 4) {
            float4 a  = *reinterpret_cast<const float4*>(&ts[r][k]);
            float4 w0 = *reinterpret_cast<const float4*>(W2 + (k + 0) * HH + cg);
            float4 w1 = *reinterpret_cast<const float4*>(W2 + (k + 1) * HH + cg);
            float4 w2 = *reinterpret_cast<const float4*>(W2 + (k + 2) * HH + cg);
            float4 w3 = *reinterpret_cast<const float4*>(W2 + (k + 3) * HH + cg);
            acc.x += a.x * w0.x + a.y * w1.x + a.z * w2.x + a.w * w3.x;
            acc.y += a.x * w0.y + a.y * w1.y + a.z * w2.y + a.w * w3.y;
            acc.z += a.x * w0.z + a.y * w1.z + a.z * w2.z + a.w * w3.z;
            acc.w += a.x * w0.w + a.y * w1.w + a.z * w2.w + a.w * w3.w;
        }
        *reinterpret_cast<float4*>(&pp[ks][r][cg]) = acc;
    }
    __syncthreads();
    if (ks == 0) {
        float4 p0 = *reinterpret_cast<const float4*>(&pp[0][r][cg]);
        float4 p1 = *reinterpret_cast<const float4*>(&pp[1][r][cg]);
        float4 p2 = *reinterpret_cast<const float4*>(&pp[2][r][cg]);
        float4 p3 = *reinterpret_cast<const float4*>(&pp[3][r][cg]);
        float4 bv = *reinterpret_cast<const float4*>(b2 + cg);
        float4 h;
        h.x = (p0.x + p1.x) + (p2.x + p3.x) + bv.x;
        h.y = (p0.y + p1.y) + (p2.y + p3.y) + bv.y;
        h.z = (p0.z + p1.z) + (p2.z + p3.z) + bv.z;
        h.w = (p0.w + p1.w) + (p2.w + p3.w) + bv.w;
        *reinterpret_cast<float4*>(&hs[r][cg]) = h;
    }
    __syncthreads();

    // GEMM3: ks>>1 selects ei (0) / ejb (1); ks&1 selects k-half of 32
    {
        const float* Wb = Wa1 + (ks >> 1) * HH * HH;
        float4 acc = make_float4(0.f, 0.f, 0.f, 0.f);
        const int k0 = (ks & 1) * 32;
        #pragma unroll
        for (int k = k0; k < k0 + 32; k += 4) {
            float4 a  = *reinterpret_cast<const float4*>(&hs[r][k]);
            float4 w0 = *reinterpret_cast<const float4*>(Wb + (k + 0) * HH + cg);
            float4 w1 = *reinterpret_cast<const float4*>(Wb + (k + 1) * HH + cg);
            float4 w2 = *reinterpret_cast<const float4*>(Wb + (k + 2) * HH + cg);
            float4 w3 = *reinterpret_cast<const float4*>(Wb + (k + 3) * HH + cg);
            acc.x += a.x * w0.x + a.y * w1.x + a.z * w2.x + a.w * w3.x;
            acc.y += a.x * w0.y + a.y * w1.y + a.z * w2.y + a.w * w3.y;
            acc.z += a.x * w0.z + a.y * w1.z + a.z * w2.z + a.w * w3.z;
            acc.w += a.x * w0.w + a.y * w1.w + a.z * w2.w + a.w * w3.w;
        }
        *reinterpret_cast<float4*>(&pp[ks][r][cg]) = acc;
    }
    __syncthreads();
    if (ks == 0) {
        float4 p0 = *reinterpret_cast<const float4*>(&pp[0][r][cg]);
        float4 p1 = *reinterpret_cast<const float4*>(&pp[1][r][cg]);
        float4 v;
        v.x = p0.x + p1.x; v.y = p0.y + p1.y;
        v.z = p0.z + p1.z; v.w = p0.w + p1.w;
        *reinterpret_cast<float4*>(ei + (row0 + r) * HH + cg) = v;
    } else if (ks == 2) {
        float4 p2 = *reinterpret_cast<const float4*>(&pp[2][r][cg]);
        float4 p3 = *reinterpret_cast<const float4*>(&pp[3][r][cg]);
        float4 bv = *reinterpret_cast<const float4*>(ba1 + cg);
        float4 v;
        v.x = p2.x + p3.x + bv.x; v.y = p2.y + p3.y + bv.y;
        v.z = p2.z + p3.z + bv.z; v.w = p2.w + p3.w + bv.w;
        *reinterpret_cast<float4*>(ejb + (row0 + r) * HH + cg) = v;
    }
}

// ---------------------------------------------------------------------------
// k2_pair: per unordered 32-tile pair (I<=J): for each element (row,c) compute
// BOTH raw directions in-register, symmetrize + sigmoid once, write the value
// to both mirrored outputs (transpose bounce via 4KB LDS). Plain-store
// per-block partial sum. No atomics, no fences.  528 blocks x 256 threads.
// ---------------------------------------------------------------------------
__global__ __launch_bounds__(256) void k2_pair(
    const float* __restrict__ ei, const float* __restrict__ ejb,
    const float* __restrict__ wa2, const float* __restrict__ ba2,
    const float* __restrict__ temp,
    float* __restrict__ out, float* __restrict__ partials)
{
    __shared__ float stg[4][32][68];   // 0:ei_I 1:ei_J 2:ejb_I 3:ejb_J
    __shared__ float T[32][33];        // adj transpose bounce
    __shared__ float wl[64];
    __shared__ float wsum[4];
    const int tid = threadIdx.x;

    // decode unordered pair (I<=J), I,J in [0,32)
    int I = 0, rem = blockIdx.x, rl = 32;
    while (rem >= rl) { rem -= rl; ++I; --rl; }
    const int J = I + rem;
    const int iBase = I * 32, jBase = J * 32;
    const bool off = (I != J);

    // stage 4 tiles of 32 rows x 64 cols (512 float4 each, 2 per thread)
    {
        const int rr = tid >> 4;          // 0..15
        const int cq = (tid & 15) << 2;
        const float* s0 = ei  + iBase * HH;
        const float* s1 = ei  + jBase * HH;
        const float* s2 = ejb + iBase * HH;
        const float* s3 = ejb + jBase * HH;
        #pragma unroll
        for (int l = 0; l < 2; ++l) {
            int r = rr + 16 * l;
            *reinterpret_cast<float4*>(&stg[0][r][cq]) =
                *reinterpret_cast<const float4*>(s0 + r * HH + cq);
            *reinterpret_cast<float4*>(&stg[1][r][cq]) =
                *reinterpret_cast<const float4*>(s1 + r * HH + cq);
            *reinterpret_cast<float4*>(&stg[2][r][cq]) =
                *reinterpret_cast<const float4*>(s2 + r * HH + cq);
            *reinterpret_cast<float4*>(&stg[3][r][cq]) =
                *reinterpret_cast<const float4*>(s3 + r * HH + cq);
        }
    }
    if (tid < 16) {
        *reinterpret_cast<float4*>(&wl[tid * 4]) =
            *reinterpret_cast<const float4*>(wa2 + tid * 4);
    }
    __syncthreads();

    const int c  = tid & 31;   // col within tile (per-lane)
    const int r0 = tid >> 5;   // 0..7 -> rows r0+8m (broadcast within half-wave)

    float d1[4] = {0.f, 0.f, 0.f, 0.f};   // S_raw[iBase+row][jBase+c]
    float d2[4] = {0.f, 0.f, 0.f, 0.f};   // S_raw[jBase+c][iBase+row]

    #pragma unroll
    for (int h = 0; h < HH; h += 4) {
        float4 w  = *reinterpret_cast<const float4*>(&wl[h]);
        float4 Bj = *reinterpret_cast<const float4*>(&stg[3][c][h]);  // ejb_J[c]
        float4 Ej = *reinterpret_cast<const float4*>(&stg[1][c][h]);  // ei_J[c]
        #pragma unroll
        for (int m = 0; m < 4; ++m) {
            const int row = r0 + 8 * m;
            float4 Ai = *reinterpret_cast<const float4*>(&stg[0][row][h]);  // ei_I[row]
            float4 Bi = *reinterpret_cast<const float4*>(&stg[2][row][h]);  // ejb_I[row]
            d1[m] += fmaxf(Ai.x + Bj.x, 0.f) * w.x
                   + fmaxf(Ai.y + Bj.y, 0.f) * w.y
                   + fmaxf(Ai.z + Bj.z, 0.f) * w.z
                   + fmaxf(Ai.w + Bj.w, 0.f) * w.w;
            d2[m] += fmaxf(Ej.x + Bi.x, 0.f) * w.x
                   + fmaxf(Ej.y + Bi.y, 0.f) * w.y
                   + fmaxf(Ej.z + Bi.z, 0.f) * w.z
                   + fmaxf(Ej.w + Bi.w, 0.f) * w.w;
        }
    }

    const float t = fminf(fmaxf(temp[0], 0.1f), 5.0f);
    const float invt = 1.0f / t;
    const float bb = ba2[0];

    float adj4[4];
    float lsum = 0.f;
    #pragma unroll
    for (int m = 0; m < 4; ++m) {
        const int row = r0 + 8 * m;
        float v = (0.5f * (d1[m] + d2[m]) + bb) * invt;
        float adj = 1.0f / (1.0f + expf(-v));
        adj4[m] = adj;
        out[(iBase + row) * NN + jBase + c] = adj;   // own position, coalesced
        lsum += adj;
    }

    if (off) {
        // mirrored tile (J,I) via LDS transpose bounce
        #pragma unroll
        for (int m = 0; m < 4; ++m) T[c][r0 + 8 * m] = adj4[m];
        __syncthreads();
        #pragma unroll
        for (int m = 0; m < 4; ++m) {
            const int rr = r0 + 8 * m;
            out[(jBase + rr) * NN + iBase + c] = T[rr][c];
        }
        lsum *= 2.0f;   // value counted at both mirrored positions
    }

    // deterministic per-block partial: fixed shuffle tree + fixed wave order
    float w = lsum;
    #pragma unroll
    for (int o = 32; o > 0; o >>= 1) w += __shfl_down(w, o);
    if ((tid & 63) == 0) wsum[tid >> 6] = w;
    __syncthreads();
    if (tid == 0) {
        partials[blockIdx.x] = (wsum[0] + wsum[1]) + (wsum[2] + wsum[3]);
    }
}

// ---------------------------------------------------------------------------
// k3_reduce: 1 block, fixed-order deterministic tree over 528 partials.
// ---------------------------------------------------------------------------
__global__ __launch_bounds__(256) void k3_reduce(
    const float* __restrict__ partials, float* __restrict__ out_loss)
{
    __shared__ float wsum[4];
    const int tid = threadIdx.x;
    float v = partials[tid] + partials[tid + 256];
    if (tid < 16) v += partials[tid + 512];
    #pragma unroll
    for (int o = 32; o > 0; o >>= 1) v += __shfl_down(v, o);
    if ((tid & 63) == 0) wsum[tid >> 6] = v;
    __syncthreads();
    if (tid == 0) {
        float tot = (wsum[0] + wsum[1]) + (wsum[2] + wsum[3]);
        *out_loss = 0.01f * tot / (float)(NN * NN);
    }
}

extern "C" void kernel_launch(void* const* d_in, const int* in_sizes, int n_in,
                              void* d_out, int out_size, void* d_ws, size_t ws_size,
                              hipStream_t stream)
{
    const float* x    = (const float*)d_in[0];
    const float* W1   = (const float*)d_in[1];
    const float* b1   = (const float*)d_in[2];
    const float* W2   = (const float*)d_in[3];
    const float* b2   = (const float*)d_in[4];
    const float* Wa1  = (const float*)d_in[5];
    const float* ba1  = (const float*)d_in[6];
    const float* wa2  = (const float*)d_in[7];
    const float* ba2  = (const float*)d_in[8];
    const float* temp = (const float*)d_in[9];
    float* out = (float*)d_out;

    float* ei    = (float*)d_ws;            // N*H floats
    float* ejb   = ei + NN * HH;            // N*H floats
    float* parts = ejb + NN * HH;           // NPAIRS floats

    k1_transform<<<NN / 4, 256, 0, stream>>>(x, W1, b1, W2, b2, Wa1, ba1, ei, ejb);
    k2_pair<<<NPAIRS, 256, 0, stream>>>(ei, ejb, wa2, ba2, temp, out, parts);
    k3_reduce<<<1, 256, 0, stream>>>(parts, out + NN * NN);
}

// Round 5
// 27.648 us; speedup vs baseline: 1.9371x; 1.2662x over previous
//
#include <hip/hip_runtime.h>
#include <cmath>

#define NN 1024
#define FF 512
#define HH 64
#define NPAIRS 528   // 32*33/2 unordered pairs of 32-row tiles

// ---------------------------------------------------------------------------
// k1: h = relu(x@W1 + b1) @ W2 + b2 ; ei = h@Wa1[:H] ; ejb = h@Wa1[H:] + ba1
// 256 blocks x 512 threads, 4 rows per block, 8-way k-split.
// ks = tid>>6 (0..7), r = (tid>>4)&3, cg = (tid&15)*4.
// ---------------------------------------------------------------------------
__global__ __launch_bounds__(512, 4) void k1_transform(
    const float* __restrict__ x, const float* __restrict__ W1,
    const float* __restrict__ b1, const float* __restrict__ W2,
    const float* __restrict__ b2, const float* __restrict__ Wa1,
    const float* __restrict__ ba1,
    float* __restrict__ ei, float* __restrict__ ejb)
{
    __shared__ float xs[4][516];       // 516%32==4 -> bank spread
    __shared__ float ts[4][68];
    __shared__ float hs[4][68];
    __shared__ float pp[8][4][68];     // k-split partials
    const int tid = threadIdx.x;
    const int row0 = blockIdx.x * 4;

    // stage x tile [4][512]: 512 float4, one per thread
    {
        int r = tid >> 7;
        int cc = (tid & 127) << 2;
        *reinterpret_cast<float4*>(&xs[r][cc]) =
            *reinterpret_cast<const float4*>(x + (row0 + r) * FF + cc);
    }
    __syncthreads();

    const int ks = tid >> 6;          // 0..7  k-split eighth
    const int r  = (tid >> 4) & 3;    // row 0..3
    const int cg = (tid & 15) << 2;   // col group of 4

    // GEMM1 partial: k in [ks*64, ks*64+64)  (16 iters)
    {
        float4 acc = make_float4(0.f, 0.f, 0.f, 0.f);
        const int k0 = ks * 64;
        #pragma unroll 4
        for (int k = k0; k < k0 + 64; k += 4) {
            float4 a  = *reinterpret_cast<const float4*>(&xs[r][k]);
            float4 w0 = *reinterpret_cast<const float4*>(W1 + (k + 0) * HH + cg);
            float4 w1 = *reinterpret_cast<const float4*>(W1 + (k + 1) * HH + cg);
            float4 w2 = *reinterpret_cast<const float4*>(W1 + (k + 2) * HH + cg);
            float4 w3 = *reinterpret_cast<const float4*>(W1 + (k + 3) * HH + cg);
            acc.x += a.x * w0.x + a.y * w1.x + a.z * w2.x + a.w * w3.x;
            acc.y += a.x * w0.y + a.y * w1.y + a.z * w2.y + a.w * w3.y;
            acc.z += a.x * w0.z + a.y * w1.z + a.z * w2.z + a.w * w3.z;
            acc.w += a.x * w0.w + a.y * w1.w + a.z * w2.w + a.w * w3.w;
        }
        *reinterpret_cast<float4*>(&pp[ks][r][cg]) = acc;
    }
    __syncthreads();
    if (ks == 0) {
        float4 s0 = *reinterpret_cast<const float4*>(&pp[0][r][cg]);
        #pragma unroll
        for (int q = 1; q < 8; ++q) {
            float4 p = *reinterpret_cast<const float4*>(&pp[q][r][cg]);
            s0.x += p.x; s0.y += p.y; s0.z += p.z; s0.w += p.w;
        }
        float4 bv = *reinterpret_cast<const float4*>(b1 + cg);
        float4 t;
        t.x = fmaxf(s0.x + bv.x, 0.f);
        t.y = fmaxf(s0.y + bv.y, 0.f);
        t.z = fmaxf(s0.z + bv.z, 0.f);
        t.w = fmaxf(s0.w + bv.w, 0.f);
        *reinterpret_cast<float4*>(&ts[r][cg]) = t;
    }
    __syncthreads();

    // GEMM2 partial: k in [ks*8, ks*8+8)  (2 iters)
    {
        float4 acc = make_float4(0.f, 0.f, 0.f, 0.f);
        const int k0 = ks * 8;
        #pragma unroll
        for (int k = k0; k < k0 + 8; k += 4) {
            float4 a  = *reinterpret_cast<const float4*>(&ts[r][k]);
            float4 w0 = *reinterpret_cast<const float4*>(W2 + (k + 0) * HH + cg);
            float4 w1 = *reinterpret_cast<const float4*>(W2 + (k + 1) * HH + cg);
            float4 w2 = *reinterpret_cast<const float4*>(W2 + (k + 2) * HH + cg);
            float4 w3 = *reinterpret_cast<const float4*>(W2 + (k + 3) * HH + cg);
            acc.x += a.x * w0.x + a.y * w1.x + a.z * w2.x + a.w * w3.x;
            acc.y += a.x * w0.y + a.y * w1.y + a.z * w2.y + a.w * w3.y;
            acc.z += a.x * w0.z + a.y * w1.z + a.z * w2.z + a.w * w3.z;
            acc.w += a.x * w0.w + a.y * w1.w + a.z * w2.w + a.w * w3.w;
        }
        *reinterpret_cast<float4*>(&pp[ks][r][cg]) = acc;
    }
    __syncthreads();
    if (ks == 0) {
        float4 s0 = *reinterpret_cast<const float4*>(&pp[0][r][cg]);
        #pragma unroll
        for (int q = 1; q < 8; ++q) {
            float4 p = *reinterpret_cast<const float4*>(&pp[q][r][cg]);
            s0.x += p.x; s0.y += p.y; s0.z += p.z; s0.w += p.w;
        }
        float4 bv = *reinterpret_cast<const float4*>(b2 + cg);
        float4 h;
        h.x = s0.x + bv.x; h.y = s0.y + bv.y;
        h.z = s0.z + bv.z; h.w = s0.w + bv.w;
        *reinterpret_cast<float4*>(&hs[r][cg]) = h;
    }
    __syncthreads();

    // GEMM3: ks>>2 selects ei (0) / ejb (1); ks&3 selects k-quarter of 16
    {
        const float* Wb = Wa1 + (ks >> 2) * HH * HH;
        float4 acc = make_float4(0.f, 0.f, 0.f, 0.f);
        const int k0 = (ks & 3) * 16;
        #pragma unroll
        for (int k = k0; k < k0 + 16; k += 4) {
            float4 a  = *reinterpret_cast<const float4*>(&hs[r][k]);
            float4 w0 = *reinterpret_cast<const float4*>(Wb + (k + 0) * HH + cg);
            float4 w1 = *reinterpret_cast<const float4*>(Wb + (k + 1) * HH + cg);
            float4 w2 = *reinterpret_cast<const float4*>(Wb + (k + 2) * HH + cg);
            float4 w3 = *reinterpret_cast<const float4*>(Wb + (k + 3) * HH + cg);
            acc.x += a.x * w0.x + a.y * w1.x + a.z * w2.x + a.w * w3.x;
            acc.y += a.x * w0.y + a.y * w1.y + a.z * w2.y + a.w * w3.y;
            acc.z += a.x * w0.z + a.y * w1.z + a.z * w2.z + a.w * w3.z;
            acc.w += a.x * w0.w + a.y * w1.w + a.z * w2.w + a.w * w3.w;
        }
        *reinterpret_cast<float4*>(&pp[ks][r][cg]) = acc;
    }
    __syncthreads();
    if (ks == 0) {
        float4 s0 = *reinterpret_cast<const float4*>(&pp[0][r][cg]);
        #pragma unroll
        for (int q = 1; q < 4; ++q) {
            float4 p = *reinterpret_cast<const float4*>(&pp[q][r][cg]);
            s0.x += p.x; s0.y += p.y; s0.z += p.z; s0.w += p.w;
        }
        *reinterpret_cast<float4*>(ei + (row0 + r) * HH + cg) = s0;
    } else if (ks == 4) {
        float4 s0 = *reinterpret_cast<const float4*>(&pp[4][r][cg]);
        #pragma unroll
        for (int q = 5; q < 8; ++q) {
            float4 p = *reinterpret_cast<const float4*>(&pp[q][r][cg]);
            s0.x += p.x; s0.y += p.y; s0.z += p.z; s0.w += p.w;
        }
        float4 bv = *reinterpret_cast<const float4*>(ba1 + cg);
        s0.x += bv.x; s0.y += bv.y; s0.z += bv.z; s0.w += bv.w;
        *reinterpret_cast<float4*>(ejb + (row0 + r) * HH + cg) = s0;
    }
}

// ---------------------------------------------------------------------------
// k2_pair: per unordered 32-tile pair (I<=J): compute BOTH raw directions
// in-register, symmetrize + sigmoid once, write both mirrored outputs
// (transpose bounce via LDS). Plain-store per-block partial sums.
// 528 blocks x 256 threads.
// ---------------------------------------------------------------------------
__global__ __launch_bounds__(256, 4) void k2_pair(
    const float* __restrict__ ei, const float* __restrict__ ejb,
    const float* __restrict__ wa2, const float* __restrict__ ba2,
    const float* __restrict__ temp,
    float* __restrict__ out, float* __restrict__ partials)
{
    __shared__ float stg[4][32][68];   // 0:ei_I 1:ei_J 2:ejb_I 3:ejb_J
    __shared__ float T[32][33];        // adj transpose bounce
    __shared__ float wl[64];
    __shared__ float wsum[4];
    const int tid = threadIdx.x;

    // decode unordered pair (I<=J), I,J in [0,32)
    int I = 0, rem = blockIdx.x, rl = 32;
    while (rem >= rl) { rem -= rl; ++I; --rl; }
    const int J = I + rem;
    const int iBase = I * 32, jBase = J * 32;
    const bool off = (I != J);

    // stage 4 tiles of 32 rows x 64 cols (512 float4 each, 2 per thread)
    {
        const int rr = tid >> 4;          // 0..15
        const int cq = (tid & 15) << 2;
        const float* s0 = ei  + iBase * HH;
        const float* s1 = ei  + jBase * HH;
        const float* s2 = ejb + iBase * HH;
        const float* s3 = ejb + jBase * HH;
        #pragma unroll
        for (int l = 0; l < 2; ++l) {
            int r = rr + 16 * l;
            *reinterpret_cast<float4*>(&stg[0][r][cq]) =
                *reinterpret_cast<const float4*>(s0 + r * HH + cq);
            *reinterpret_cast<float4*>(&stg[1][r][cq]) =
                *reinterpret_cast<const float4*>(s1 + r * HH + cq);
            *reinterpret_cast<float4*>(&stg[2][r][cq]) =
                *reinterpret_cast<const float4*>(s2 + r * HH + cq);
            *reinterpret_cast<float4*>(&stg[3][r][cq]) =
                *reinterpret_cast<const float4*>(s3 + r * HH + cq);
        }
    }
    if (tid < 16) {
        *reinterpret_cast<float4*>(&wl[tid * 4]) =
            *reinterpret_cast<const float4*>(wa2 + tid * 4);
    }
    __syncthreads();

    const int c  = tid & 31;   // col within tile (per-lane)
    const int r0 = tid >> 5;   // 0..7 -> rows r0+8m (broadcast within half-wave)

    float d1[4] = {0.f, 0.f, 0.f, 0.f};   // S_raw[iBase+row][jBase+c]
    float d2[4] = {0.f, 0.f, 0.f, 0.f};   // S_raw[jBase+c][iBase+row]

    #pragma unroll 4
    for (int h = 0; h < HH; h += 4) {
        float4 w  = *reinterpret_cast<const float4*>(&wl[h]);
        {
            float4 Bj = *reinterpret_cast<const float4*>(&stg[3][c][h]);  // ejb_J[c]
            #pragma unroll
            for (int m = 0; m < 4; ++m) {
                float4 Ai = *reinterpret_cast<const float4*>(&stg[0][r0 + 8 * m][h]);
                d1[m] += fmaxf(Ai.x + Bj.x, 0.f) * w.x
                       + fmaxf(Ai.y + Bj.y, 0.f) * w.y
                       + fmaxf(Ai.z + Bj.z, 0.f) * w.z
                       + fmaxf(Ai.w + Bj.w, 0.f) * w.w;
            }
        }
        {
            float4 Ej = *reinterpret_cast<const float4*>(&stg[1][c][h]);  // ei_J[c]
            #pragma unroll
            for (int m = 0; m < 4; ++m) {
                float4 Bi = *reinterpret_cast<const float4*>(&stg[2][r0 + 8 * m][h]);
                d2[m] += fmaxf(Ej.x + Bi.x, 0.f) * w.x
                       + fmaxf(Ej.y + Bi.y, 0.f) * w.y
                       + fmaxf(Ej.z + Bi.z, 0.f) * w.z
                       + fmaxf(Ej.w + Bi.w, 0.f) * w.w;
            }
        }
    }

    const float t = fminf(fmaxf(temp[0], 0.1f), 5.0f);
    const float invt = 1.0f / t;
    const float bb = ba2[0];

    float adj4[4];
    float lsum = 0.f;
    #pragma unroll
    for (int m = 0; m < 4; ++m) {
        const int row = r0 + 8 * m;
        float v = (0.5f * (d1[m] + d2[m]) + bb) * invt;
        float adj = 1.0f / (1.0f + __expf(-v));
        adj4[m] = adj;
        out[(iBase + row) * NN + jBase + c] = adj;   // own position, coalesced
        lsum += adj;
    }

    if (off) {
        // mirrored tile (J,I) via LDS transpose bounce
        #pragma unroll
        for (int m = 0; m < 4; ++m) T[c][r0 + 8 * m] = adj4[m];
        __syncthreads();
        #pragma unroll
        for (int m = 0; m < 4; ++m) {
            const int rr = r0 + 8 * m;
            out[(jBase + rr) * NN + iBase + c] = T[rr][c];
        }
        lsum *= 2.0f;   // value counted at both mirrored positions
    }

    // deterministic per-block partial: fixed shuffle tree + fixed wave order
    float w = lsum;
    #pragma unroll
    for (int o = 32; o > 0; o >>= 1) w += __shfl_down(w, o);
    if ((tid & 63) == 0) wsum[tid >> 6] = w;
    __syncthreads();
    if (tid == 0) {
        partials[blockIdx.x] = (wsum[0] + wsum[1]) + (wsum[2] + wsum[3]);
    }
}

// ---------------------------------------------------------------------------
// k3_reduce: 1 block, fixed-order deterministic tree over 528 partials.
// ---------------------------------------------------------------------------
__global__ __launch_bounds__(256) void k3_reduce(
    const float* __restrict__ partials, float* __restrict__ out_loss)
{
    __shared__ float wsum[4];
    const int tid = threadIdx.x;
    float v = partials[tid] + partials[tid + 256];
    if (tid < 16) v += partials[tid + 512];
    #pragma unroll
    for (int o = 32; o > 0; o >>= 1) v += __shfl_down(v, o);
    if ((tid & 63) == 0) wsum[tid >> 6] = v;
    __syncthreads();
    if (tid == 0) {
        float tot = (wsum[0] + wsum[1]) + (wsum[2] + wsum[3]);
        *out_loss = 0.01f * tot / (float)(NN * NN);
    }
}

extern "C" void kernel_launch(void* const* d_in, const int* in_sizes, int n_in,
                              void* d_out, int out_size, void* d_ws, size_t ws_size,
                              hipStream_t stream)
{
    const float* x    = (const float*)d_in[0];
    const float* W1   = (const float*)d_in[1];
    const float* b1   = (const float*)d_in[2];
    const float* W2   = (const float*)d_in[3];
    const float* b2   = (const float*)d_in[4];
    const float* Wa1  = (const float*)d_in[5];
    const float* ba1  = (const float*)d_in[6];
    const float* wa2  = (const float*)d_in[7];
    const float* ba2  = (const float*)d_in[8];
    const float* temp = (const float*)d_in[9];
    float* out = (float*)d_out;

    float* ei    = (float*)d_ws;            // N*H floats
    float* ejb   = ei + NN * HH;            // N*H floats
    float* parts = ejb + NN * HH;           // NPAIRS floats

    k1_transform<<<NN / 4, 512, 0, stream>>>(x, W1, b1, W2, b2, Wa1, ba1, ei, ejb);
    k2_pair<<<NPAIRS, 256, 0, stream>>>(ei, ejb, wa2, ba2, temp, out, parts);
    k3_reduce<<<1, 256, 0, stream>>>(parts, out + NN * NN);
}